// Round 2
// baseline (619.123 us; speedup 1.0000x reference)
//
#include <hip/hip_runtime.h>

#define NUM_HEADS 8

// ---- K0: cumulative complex rotations frv[l][d], l=0..3 (l=3 = identity) ----
__global__ void k_frv(const float2* __restrict__ rvec, float2* __restrict__ frv) {
    int d = threadIdx.x;
    if (d >= 32) return;
    float2 a = rvec[d];        // r_vec[0, d, :]
    float2 b = rvec[32 + d];   // r_vec[1, d, :]
    float na = rsqrtf(a.x*a.x + a.y*a.y); a.x *= na; a.y *= na;
    float nb = rsqrtf(b.x*b.x + b.y*b.y); b.x *= nb; b.y *= nb;
    // ETYPES=[0,2,1]: fr3=1, fr2=conj(rv0), fr1=fr2*rv1, fr0=fr1*rv0
    float2 fr3 = make_float2(1.f, 0.f);
    float2 fr2 = make_float2(a.x, -a.y);
    float2 fr1 = make_float2(fr2.x*b.x - fr2.y*b.y, fr2.x*b.y + fr2.y*b.x);
    float2 fr0 = make_float2(fr1.x*a.x - fr1.y*a.y, fr1.x*a.y + fr1.y*a.x);
    frv[d] = fr0; frv[32+d] = fr1; frv[64+d] = fr2; frv[96+d] = fr3;
}

// ---- K1: per-edge hidden + attention logits + segment-max + degree counts ----
__global__ __launch_bounds__(256) void k_edge(
    const float2* __restrict__ feat,    // f32, row = 32 float2 (64 floats)
    const float2* __restrict__ frv_g,
    const float2* __restrict__ w1_g,    // attn1_w (8,64) f32 = 256 float2
    const float2* __restrict__ w2_g,    // attn2   (8,64) f32 = 256 float2
    const int4*   __restrict__ emi,
    const int*    __restrict__ edge_dst,
    float2*       __restrict__ hidden,  // E*32 f32 complex
    float*        __restrict__ a_buf,   // E*8
    unsigned*     __restrict__ amax,    // N*8 (ordered-uint encoded max)
    int*          __restrict__ counts,  // N
    int E)
{
    __shared__ float2 s_frv[96];
    __shared__ float2 s_w1[256];
    __shared__ float2 s_w2[256];
    int tid = threadIdx.x;
    if (tid < 96) s_frv[tid] = frv_g[tid];
    s_w1[tid] = w1_g[tid];
    s_w2[tid] = w2_g[tid];
    __syncthreads();

    int e = blockIdx.x * 8 + (tid >> 5);
    if (e >= E) return;
    int lane = tid & 31;

    int4 idx = emi[e];
    float2 f0 = feat[(size_t)idx.x * 32 + lane];
    float2 f1 = feat[(size_t)idx.y * 32 + lane];
    float2 f2 = feat[(size_t)idx.z * 32 + lane];
    float2 c3 = feat[(size_t)idx.w * 32 + lane];  // l=3 row == center row

    float2 acc = c3;  // frv[3] = identity
    float2 q;
    q = s_frv[lane];      acc.x += f0.x*q.x - f0.y*q.y; acc.y += f0.x*q.y + f0.y*q.x;
    q = s_frv[32+lane];   acc.x += f1.x*q.x - f1.y*q.y; acc.y += f1.x*q.y + f1.y*q.x;
    q = s_frv[64+lane];   acc.x += f2.x*q.x - f2.y*q.y; acc.y += f2.x*q.y + f2.y*q.x;
    float2 h = make_float2(acc.x * 0.25f, acc.y * 0.25f);
    hidden[(size_t)e * 32 + lane] = h;

    float p[NUM_HEADS];
    #pragma unroll
    for (int hh = 0; hh < NUM_HEADS; ++hh) {
        float2 w1 = s_w1[hh*32 + lane], w2 = s_w2[hh*32 + lane];
        p[hh] = c3.x*w1.x + c3.y*w1.y + h.x*w2.x + h.y*w2.y;
    }
    #pragma unroll
    for (int hh = 0; hh < NUM_HEADS; ++hh) {
        #pragma unroll
        for (int off = 16; off > 0; off >>= 1)
            p[hh] += __shfl_xor(p[hh], off, 32);
    }
    if (lane == 0) {
        int dst = edge_dst[e];
        atomicAdd(&counts[dst], 1);
        #pragma unroll
        for (int hh = 0; hh < NUM_HEADS; ++hh) {
            float a = p[hh];
            a = a > 0.f ? a : 0.01f * a;           // LeakyReLU
            a_buf[(size_t)e * 8 + hh] = a;
            unsigned enc = __float_as_uint(a);
            enc = (enc & 0x80000000u) ? ~enc : (enc | 0x80000000u);
            atomicMax(&amax[(size_t)dst * 8 + hh], enc);
        }
    }
}

// ---- K2: exclusive scan of degree counts -> CSR offsets (+cursor copy) ----
__global__ void k_scan(const int* __restrict__ counts, int* __restrict__ offsets,
                       int* __restrict__ cursor, int N) {
    __shared__ int ssum[1024];
    int t = threadIdx.x;
    int chunk = (N + 1023) >> 10;
    int start = t * chunk;
    int end = start + chunk; if (end > N) end = N; if (start > N) start = N;
    int s = 0;
    for (int i = start; i < end; ++i) s += counts[i];
    ssum[t] = s;
    __syncthreads();
    for (int off = 1; off < 1024; off <<= 1) {
        int v = (t >= off) ? ssum[t - off] : 0;
        __syncthreads();
        ssum[t] += v;
        __syncthreads();
    }
    int run = (t == 0) ? 0 : ssum[t - 1];
    for (int i = start; i < end; ++i) {
        offsets[i] = run; cursor[i] = run;
        run += counts[i];
    }
    if (t == 1023) offsets[N] = run;  // == E
}

// ---- K3: bucket edge ids by dst ----
__global__ void k_fill(const int* __restrict__ edge_dst, int* __restrict__ cursor,
                       int* __restrict__ edge_ids, int E) {
    int e = blockIdx.x * 256 + threadIdx.x;
    if (e >= E) return;
    int pos = atomicAdd(&cursor[edge_dst[e]], 1);
    edge_ids[pos] = e;
}

// ---- K4: exp(a - amax[dst]) and segment sum ----
__global__ void k_soft(const int* __restrict__ edge_dst,
                       const unsigned* __restrict__ amax,
                       float* __restrict__ a_buf,   // in: a, out: aexp
                       float* __restrict__ asum,
                       int total) {
    int i = blockIdx.x * 256 + threadIdx.x;
    if (i >= total) return;
    int e = i >> 3, hh = i & 7;
    int dst = edge_dst[e];
    unsigned enc = amax[dst * 8 + hh];
    float m = (enc & 0x80000000u) ? __uint_as_float(enc & 0x7fffffffu)
                                  : __uint_as_float(~enc);
    float v = expf(a_buf[i] - m);
    a_buf[i] = v;
    unsafeAtomicAdd(&asum[dst * 8 + hh], v);
}

// ---- K5: per-node CSR gather, normalize, accumulate, write f32 out ----
__global__ __launch_bounds__(256) void k_out(
    const float2* __restrict__ hidden,
    const float*  __restrict__ aexp,
    const float*  __restrict__ asum,
    const int*    __restrict__ offsets,
    const int*    __restrict__ edge_ids,
    float2*       __restrict__ out,      // f32 (N,8,64) = N*8*32 float2
    int N)
{
    int tid = threadIdx.x;
    int n = blockIdx.x * 8 + (tid >> 5);
    if (n >= N) return;
    int lane = tid & 31;
    int beg = offsets[n], end = offsets[n + 1];
    float rinv[NUM_HEADS];
    #pragma unroll
    for (int hh = 0; hh < NUM_HEADS; ++hh)
        rinv[hh] = 1.0f / asum[(size_t)n * 8 + hh];   // inf if degree 0 — unused then
    float2 acc[NUM_HEADS];
    #pragma unroll
    for (int hh = 0; hh < NUM_HEADS; ++hh) acc[hh] = make_float2(0.f, 0.f);
    for (int j = beg; j < end; ++j) {
        int e = edge_ids[j];
        float2 hv = hidden[(size_t)e * 32 + lane];
        #pragma unroll
        for (int hh = 0; hh < NUM_HEADS; ++hh) {
            float w = aexp[(size_t)e * 8 + hh] * rinv[hh];
            acc[hh].x += hv.x * w;
            acc[hh].y += hv.y * w;
        }
    }
    #pragma unroll
    for (int hh = 0; hh < NUM_HEADS; ++hh)
        out[((size_t)n * 8 + hh) * 32 + lane] = acc[hh];
}

extern "C" void kernel_launch(void* const* d_in, const int* in_sizes, int n_in,
                              void* d_out, int out_size, void* d_ws, size_t ws_size,
                              hipStream_t stream) {
    const float2* feat = (const float2*)d_in[0];   // features f32 (N,64)
    const float2* rvec = (const float2*)d_in[1];   // r_vec f32 (2,32,2)
    const float2* w1   = (const float2*)d_in[2];   // attn1_w f32 (8,64)
    const float2* w2   = (const float2*)d_in[3];   // attn2 f32 (1,8,64)
    const int4*   emi  = (const int4*)d_in[4];     // (E,4) int32
    const int* edge_dst = (const int*)d_in[5];     // (E,) int32

    int N = in_sizes[0] / 64;
    int E = in_sizes[4] / 4;

    char* w = (char*)d_ws;
    float2*   frv      = (float2*)w;                        // 128 float2 = 1 KiB
    float*    hidden   = (float*)(w + 1024);                // E*64 f32
    float*    a_buf    = hidden + (size_t)E * 64;           // E*8 f32
    unsigned* amax     = (unsigned*)(a_buf + (size_t)E * 8);// N*8 u32
    float*    asum     = (float*)(amax + (size_t)N * 8);    // N*8 f32
    int*      counts   = (int*)(asum + (size_t)N * 8);      // N
    int*      offsets  = counts + N;                        // N+1
    int*      cursor   = offsets + N + 1;                   // N
    int*      edge_ids = cursor + N;                        // E

    hipMemsetAsync(amax,   0, (size_t)N * 8 * 4, stream);
    hipMemsetAsync(asum,   0, (size_t)N * 8 * 4, stream);
    hipMemsetAsync(counts, 0, (size_t)N * 4, stream);

    k_frv<<<1, 64, 0, stream>>>(rvec, frv);
    k_edge<<<(E + 7) / 8, 256, 0, stream>>>(feat, frv, w1, w2, emi, edge_dst,
                                            (float2*)hidden, a_buf, amax, counts, E);
    k_scan<<<1, 1024, 0, stream>>>(counts, offsets, cursor, N);
    k_fill<<<(E + 255) / 256, 256, 0, stream>>>(edge_dst, cursor, edge_ids, E);
    k_soft<<<(E * 8 + 255) / 256, 256, 0, stream>>>(edge_dst, amax, a_buf, asum, E * 8);
    k_out<<<(N + 7) / 8, 256, 0, stream>>>((const float2*)hidden, a_buf, asum,
                                           offsets, edge_ids, (float2*)d_out, N);
}

// Round 3
// 407.948 us; speedup vs baseline: 1.5176x; 1.5176x over previous
//
#include <hip/hip_runtime.h>

#define NUM_HEADS 8

// ---- K0: cumulative complex rotations frv[l][d], l=0..3 (l=3 = identity) ----
__global__ void k_frv(const float2* __restrict__ rvec, float2* __restrict__ frv) {
    int d = threadIdx.x;
    if (d >= 32) return;
    float2 a = rvec[d];        // r_vec[0, d, :]
    float2 b = rvec[32 + d];   // r_vec[1, d, :]
    float na = rsqrtf(a.x*a.x + a.y*a.y); a.x *= na; a.y *= na;
    float nb = rsqrtf(b.x*b.x + b.y*b.y); b.x *= nb; b.y *= nb;
    // ETYPES=[0,2,1]: fr3=1, fr2=conj(rv0), fr1=fr2*rv1, fr0=fr1*rv0
    float2 fr3 = make_float2(1.f, 0.f);
    float2 fr2 = make_float2(a.x, -a.y);
    float2 fr1 = make_float2(fr2.x*b.x - fr2.y*b.y, fr2.x*b.y + fr2.y*b.x);
    float2 fr0 = make_float2(fr1.x*a.x - fr1.y*a.y, fr1.x*a.y + fr1.y*a.x);
    frv[d] = fr0; frv[32+d] = fr1; frv[64+d] = fr2; frv[96+d] = fr3;
}

// ---- K1: per-edge hidden + attention logits + segment-max + degree counts ----
__global__ __launch_bounds__(256) void k_edge(
    const float2* __restrict__ feat,    // f32, row = 32 float2 (64 floats)
    const float2* __restrict__ frv_g,
    const float2* __restrict__ w1_g,    // attn1_w (8,64) f32 = 256 float2
    const float2* __restrict__ w2_g,    // attn2   (8,64) f32 = 256 float2
    const int4*   __restrict__ emi,
    const int*    __restrict__ edge_dst,
    float2*       __restrict__ hidden,  // E*32 f32 complex
    float*        __restrict__ a_buf,   // E*8
    unsigned*     __restrict__ amax,    // N*8 (ordered-uint encoded max)
    int*          __restrict__ counts,  // N
    int E)
{
    __shared__ float2 s_frv[96];
    __shared__ float2 s_w1[256];
    __shared__ float2 s_w2[256];
    int tid = threadIdx.x;
    if (tid < 96) s_frv[tid] = frv_g[tid];
    s_w1[tid] = w1_g[tid];
    s_w2[tid] = w2_g[tid];
    __syncthreads();

    int e = blockIdx.x * 8 + (tid >> 5);
    if (e >= E) return;
    int lane = tid & 31;

    int4 idx = emi[e];
    float2 f0 = feat[(size_t)idx.x * 32 + lane];
    float2 f1 = feat[(size_t)idx.y * 32 + lane];
    float2 f2 = feat[(size_t)idx.z * 32 + lane];
    float2 c3 = feat[(size_t)idx.w * 32 + lane];  // l=3 row == center row

    float2 acc = c3;  // frv[3] = identity
    float2 q;
    q = s_frv[lane];      acc.x += f0.x*q.x - f0.y*q.y; acc.y += f0.x*q.y + f0.y*q.x;
    q = s_frv[32+lane];   acc.x += f1.x*q.x - f1.y*q.y; acc.y += f1.x*q.y + f1.y*q.x;
    q = s_frv[64+lane];   acc.x += f2.x*q.x - f2.y*q.y; acc.y += f2.x*q.y + f2.y*q.x;
    float2 h = make_float2(acc.x * 0.25f, acc.y * 0.25f);
    hidden[(size_t)e * 32 + lane] = h;

    float p[NUM_HEADS];
    #pragma unroll
    for (int hh = 0; hh < NUM_HEADS; ++hh) {
        float2 w1 = s_w1[hh*32 + lane], w2 = s_w2[hh*32 + lane];
        p[hh] = c3.x*w1.x + c3.y*w1.y + h.x*w2.x + h.y*w2.y;
    }
    #pragma unroll
    for (int hh = 0; hh < NUM_HEADS; ++hh) {
        #pragma unroll
        for (int off = 16; off > 0; off >>= 1)
            p[hh] += __shfl_xor(p[hh], off, 32);
    }
    if (lane == 0) {
        int dst = edge_dst[e];
        atomicAdd(&counts[dst], 1);
        #pragma unroll
        for (int hh = 0; hh < NUM_HEADS; ++hh) {
            float a = p[hh];
            a = a > 0.f ? a : 0.01f * a;           // LeakyReLU
            a_buf[(size_t)e * 8 + hh] = a;
            unsigned enc = __float_as_uint(a);
            enc = (enc & 0x80000000u) ? ~enc : (enc | 0x80000000u);
            atomicMax(&amax[(size_t)dst * 8 + hh], enc);
        }
    }
}

// ---- K2a: per-tile (1024) exclusive scan; tile sums out ----
__global__ __launch_bounds__(256) void k_scan_a(
    const int* __restrict__ counts, int* __restrict__ offsets,
    int* __restrict__ blocksums, int N)
{
    __shared__ int s[256];
    int t = threadIdx.x;
    int base = blockIdx.x * 1024 + t * 4;
    int v0 = (base     < N) ? counts[base]     : 0;
    int v1 = (base + 1 < N) ? counts[base + 1] : 0;
    int v2 = (base + 2 < N) ? counts[base + 2] : 0;
    int v3 = (base + 3 < N) ? counts[base + 3] : 0;
    s[t] = v0 + v1 + v2 + v3;
    __syncthreads();
    #pragma unroll
    for (int off = 1; off < 256; off <<= 1) {
        int x = (t >= off) ? s[t - off] : 0;
        __syncthreads();
        s[t] += x;
        __syncthreads();
    }
    if (t == 255) blocksums[blockIdx.x] = s[255];
    int run = (t == 0) ? 0 : s[t - 1];
    if (base     < N) offsets[base]     = run; run += v0;
    if (base + 1 < N) offsets[base + 1] = run; run += v1;
    if (base + 2 < N) offsets[base + 2] = run; run += v2;
    if (base + 3 < N) offsets[base + 3] = run;
}

// ---- K2b: exclusive scan of tile sums (B <= 1024), one block ----
__global__ __launch_bounds__(1024) void k_scan_b(
    int* __restrict__ blocksums, int* __restrict__ total, int B)
{
    __shared__ int s[1024];
    int t = threadIdx.x;
    s[t] = (t < B) ? blocksums[t] : 0;
    __syncthreads();
    #pragma unroll
    for (int off = 1; off < 1024; off <<= 1) {
        int x = (t >= off) ? s[t - off] : 0;
        __syncthreads();
        s[t] += x;
        __syncthreads();
    }
    if (t < B) blocksums[t] = (t == 0) ? 0 : s[t - 1];
    if (t == 1023) *total = s[1023];   // == E
}

// ---- K2c: add tile prefix; emit cursor copy and offsets[N] ----
__global__ __launch_bounds__(256) void k_scan_c(
    int* __restrict__ offsets, int* __restrict__ cursor,
    const int* __restrict__ blocksums, const int* __restrict__ total, int N)
{
    int i = blockIdx.x * 256 + threadIdx.x;
    if (i < N) {
        int v = offsets[i] + blocksums[i >> 10];
        offsets[i] = v;
        cursor[i] = v;
    }
    if (i == 0) offsets[N] = *total;
}

// ---- K3: bucket edge ids by dst ----
__global__ void k_fill(const int* __restrict__ edge_dst, int* __restrict__ cursor,
                       int* __restrict__ edge_ids, int E) {
    int e = blockIdx.x * 256 + threadIdx.x;
    if (e >= E) return;
    int pos = atomicAdd(&cursor[edge_dst[e]], 1);
    edge_ids[pos] = e;
}

// ---- K4: exp(a - amax[dst]) and segment sum ----
__global__ void k_soft(const int* __restrict__ edge_dst,
                       const unsigned* __restrict__ amax,
                       float* __restrict__ a_buf,   // in: a, out: aexp
                       float* __restrict__ asum,
                       int total) {
    int i = blockIdx.x * 256 + threadIdx.x;
    if (i >= total) return;
    int e = i >> 3, hh = i & 7;
    int dst = edge_dst[e];
    unsigned enc = amax[dst * 8 + hh];
    float m = (enc & 0x80000000u) ? __uint_as_float(enc & 0x7fffffffu)
                                  : __uint_as_float(~enc);
    float v = expf(a_buf[i] - m);
    a_buf[i] = v;
    unsafeAtomicAdd(&asum[dst * 8 + hh], v);
}

// ---- K5: per-node CSR gather, normalize, accumulate, write f32 out ----
__global__ __launch_bounds__(256) void k_out(
    const float2* __restrict__ hidden,
    const float*  __restrict__ aexp,
    const float*  __restrict__ asum,
    const int*    __restrict__ offsets,
    const int*    __restrict__ edge_ids,
    float2*       __restrict__ out,      // f32 (N,8,64) = N*8*32 float2
    int N)
{
    int tid = threadIdx.x;
    int n = blockIdx.x * 8 + (tid >> 5);
    if (n >= N) return;
    int lane = tid & 31;
    int beg = offsets[n], end = offsets[n + 1];
    float rinv[NUM_HEADS];
    #pragma unroll
    for (int hh = 0; hh < NUM_HEADS; ++hh)
        rinv[hh] = 1.0f / asum[(size_t)n * 8 + hh];   // inf if degree 0 — unused then
    float2 acc[NUM_HEADS];
    #pragma unroll
    for (int hh = 0; hh < NUM_HEADS; ++hh) acc[hh] = make_float2(0.f, 0.f);
    for (int j = beg; j < end; ++j) {
        int e = edge_ids[j];
        float2 hv = hidden[(size_t)e * 32 + lane];
        #pragma unroll
        for (int hh = 0; hh < NUM_HEADS; ++hh) {
            float w = aexp[(size_t)e * 8 + hh] * rinv[hh];
            acc[hh].x += hv.x * w;
            acc[hh].y += hv.y * w;
        }
    }
    #pragma unroll
    for (int hh = 0; hh < NUM_HEADS; ++hh)
        out[((size_t)n * 8 + hh) * 32 + lane] = acc[hh];
}

extern "C" void kernel_launch(void* const* d_in, const int* in_sizes, int n_in,
                              void* d_out, int out_size, void* d_ws, size_t ws_size,
                              hipStream_t stream) {
    const float2* feat = (const float2*)d_in[0];   // features f32 (N,64)
    const float2* rvec = (const float2*)d_in[1];   // r_vec f32 (2,32,2)
    const float2* w1   = (const float2*)d_in[2];   // attn1_w f32 (8,64)
    const float2* w2   = (const float2*)d_in[3];   // attn2 f32 (1,8,64)
    const int4*   emi  = (const int4*)d_in[4];     // (E,4) int32
    const int* edge_dst = (const int*)d_in[5];     // (E,) int32

    int N = in_sizes[0] / 64;
    int E = in_sizes[4] / 4;
    int nTiles = (N + 1023) / 1024;                // <= 1024 assumed (N=100k -> 98)

    char* w = (char*)d_ws;
    float2*   frv      = (float2*)w;                        // 128 float2 = 1 KiB
    float*    hidden   = (float*)(w + 1024);                // E*64 f32
    float*    a_buf    = hidden + (size_t)E * 64;           // E*8 f32
    unsigned* amax     = (unsigned*)(a_buf + (size_t)E * 8);// N*8 u32
    float*    asum     = (float*)(amax + (size_t)N * 8);    // N*8 f32
    int*      counts   = (int*)(asum + (size_t)N * 8);      // N
    int*      offsets  = counts + N;                        // N+1
    int*      cursor   = offsets + N + 1;                   // N
    int*      edge_ids = cursor + N;                        // E
    int*      blocksums= edge_ids + E;                      // nTiles
    int*      total    = blocksums + 1024;                  // 1

    hipMemsetAsync(amax,   0, (size_t)N * 8 * 4, stream);
    hipMemsetAsync(asum,   0, (size_t)N * 8 * 4, stream);
    hipMemsetAsync(counts, 0, (size_t)N * 4, stream);

    k_frv<<<1, 64, 0, stream>>>(rvec, frv);
    k_edge<<<(E + 7) / 8, 256, 0, stream>>>(feat, frv, w1, w2, emi, edge_dst,
                                            (float2*)hidden, a_buf, amax, counts, E);
    k_scan_a<<<nTiles, 256, 0, stream>>>(counts, offsets, blocksums, N);
    k_scan_b<<<1, 1024, 0, stream>>>(blocksums, total, nTiles);
    k_scan_c<<<(N + 255) / 256, 256, 0, stream>>>(offsets, cursor, blocksums, total, N);
    k_fill<<<(E + 255) / 256, 256, 0, stream>>>(edge_dst, cursor, edge_ids, E);
    k_soft<<<(E * 8 + 255) / 256, 256, 0, stream>>>(edge_dst, amax, a_buf, asum, E * 8);
    k_out<<<(N + 7) / 8, 256, 0, stream>>>((const float2*)hidden, a_buf, asum,
                                           offsets, edge_ids, (float2*)d_out, N);
}

// Round 4
// 374.299 us; speedup vs baseline: 1.6541x; 1.0899x over previous
//
#include <hip/hip_runtime.h>

#define NUM_HEADS 8

__device__ __forceinline__ float2 cmul(float2 a, float2 b) {
    return make_float2(a.x*b.x - a.y*b.y, a.x*b.y + a.y*b.x);
}

// ---- K1: per-edge hidden + attention logits + degree counts ----
// frv (cumulative rotations) computed in the LDS prologue from r_vec directly.
__global__ __launch_bounds__(256) void k_edge(
    const float2* __restrict__ feat,    // f32, row = 32 float2 (64 floats)
    const float2* __restrict__ rvec,    // (2,32,2) f32 = 64 float2
    const float2* __restrict__ w1_g,    // attn1_w (8,64) f32 = 256 float2
    const float2* __restrict__ w2_g,    // attn2   (8,64) f32 = 256 float2
    const int4*   __restrict__ emi,
    const int*    __restrict__ edge_dst,
    float2*       __restrict__ hidden,  // E*32 f32 complex
    float*        __restrict__ a_buf,   // E*8 leaky-relu'd logits
    int*          __restrict__ counts,  // N degrees
    int E)
{
    __shared__ float2 s_frv[96];
    __shared__ float2 s_w1[256];
    __shared__ float2 s_w2[256];
    int tid = threadIdx.x;
    if (tid < 32) {
        float2 a = rvec[tid];        // r_vec[0, d, :]
        float2 b = rvec[32 + tid];   // r_vec[1, d, :]
        float na = rsqrtf(a.x*a.x + a.y*a.y); a.x *= na; a.y *= na;
        float nb = rsqrtf(b.x*b.x + b.y*b.y); b.x *= nb; b.y *= nb;
        // ETYPES=[0,2,1]: fr3=1 (implicit), fr2=conj(rv0), fr1=fr2*rv1, fr0=fr1*rv0
        float2 fr2 = make_float2(a.x, -a.y);
        float2 fr1 = cmul(fr2, b);
        float2 fr0 = cmul(fr1, a);
        s_frv[tid] = fr0; s_frv[32+tid] = fr1; s_frv[64+tid] = fr2;
    }
    s_w1[tid] = w1_g[tid];
    s_w2[tid] = w2_g[tid];
    __syncthreads();

    int e = blockIdx.x * 8 + (tid >> 5);
    if (e >= E) return;
    int lane = tid & 31;

    int4 idx = emi[e];
    float2 f0 = feat[(size_t)idx.x * 32 + lane];
    float2 f1 = feat[(size_t)idx.y * 32 + lane];
    float2 f2 = feat[(size_t)idx.z * 32 + lane];
    float2 c3 = feat[(size_t)idx.w * 32 + lane];  // l=3 row == center row

    float2 acc = c3;  // frv[3] = identity
    float2 q;
    q = s_frv[lane];      acc.x += f0.x*q.x - f0.y*q.y; acc.y += f0.x*q.y + f0.y*q.x;
    q = s_frv[32+lane];   acc.x += f1.x*q.x - f1.y*q.y; acc.y += f1.x*q.y + f1.y*q.x;
    q = s_frv[64+lane];   acc.x += f2.x*q.x - f2.y*q.y; acc.y += f2.x*q.y + f2.y*q.x;
    float2 h = make_float2(acc.x * 0.25f, acc.y * 0.25f);
    hidden[(size_t)e * 32 + lane] = h;

    float p[NUM_HEADS];
    #pragma unroll
    for (int hh = 0; hh < NUM_HEADS; ++hh) {
        float2 w1 = s_w1[hh*32 + lane], w2 = s_w2[hh*32 + lane];
        p[hh] = c3.x*w1.x + c3.y*w1.y + h.x*w2.x + h.y*w2.y;
    }
    float myv = 0.f;
    #pragma unroll
    for (int hh = 0; hh < NUM_HEADS; ++hh) {
        #pragma unroll
        for (int off = 16; off > 0; off >>= 1)
            p[hh] += __shfl_xor(p[hh], off, 32);
        if (lane == hh) myv = p[hh];
    }
    if (lane < NUM_HEADS) {
        float a = myv > 0.f ? myv : 0.01f * myv;   // LeakyReLU
        a_buf[(size_t)e * 8 + lane] = a;
    }
    if (lane == 0) atomicAdd(&counts[edge_dst[e]], 1);
}

// ---- K2a: per-tile (1024) exclusive scan; tile sums out ----
__global__ __launch_bounds__(256) void k_scan_a(
    const int* __restrict__ counts, int* __restrict__ offsets,
    int* __restrict__ blocksums, int N)
{
    __shared__ int s[256];
    int t = threadIdx.x;
    int base = blockIdx.x * 1024 + t * 4;
    int v0 = (base     < N) ? counts[base]     : 0;
    int v1 = (base + 1 < N) ? counts[base + 1] : 0;
    int v2 = (base + 2 < N) ? counts[base + 2] : 0;
    int v3 = (base + 3 < N) ? counts[base + 3] : 0;
    s[t] = v0 + v1 + v2 + v3;
    __syncthreads();
    #pragma unroll
    for (int off = 1; off < 256; off <<= 1) {
        int x = (t >= off) ? s[t - off] : 0;
        __syncthreads();
        s[t] += x;
        __syncthreads();
    }
    if (t == 255) blocksums[blockIdx.x] = s[255];
    int run = (t == 0) ? 0 : s[t - 1];
    if (base     < N) offsets[base]     = run; run += v0;
    if (base + 1 < N) offsets[base + 1] = run; run += v1;
    if (base + 2 < N) offsets[base + 2] = run; run += v2;
    if (base + 3 < N) offsets[base + 3] = run;
}

// ---- K2b: exclusive scan of tile sums (B <= 1024), one block ----
__global__ __launch_bounds__(1024) void k_scan_b(
    int* __restrict__ blocksums, int* __restrict__ total, int B)
{
    __shared__ int s[1024];
    int t = threadIdx.x;
    s[t] = (t < B) ? blocksums[t] : 0;
    __syncthreads();
    #pragma unroll
    for (int off = 1; off < 1024; off <<= 1) {
        int x = (t >= off) ? s[t - off] : 0;
        __syncthreads();
        s[t] += x;
        __syncthreads();
    }
    if (t < B) blocksums[t] = (t == 0) ? 0 : s[t - 1];
    if (t == 1023) *total = s[1023];   // == E
}

// ---- K2c: add tile prefix; emit cursor copy and offsets[N] ----
__global__ __launch_bounds__(256) void k_scan_c(
    int* __restrict__ offsets, int* __restrict__ cursor,
    const int* __restrict__ blocksums, const int* __restrict__ total, int N)
{
    int i = blockIdx.x * 256 + threadIdx.x;
    if (i < N) {
        int v = offsets[i] + blocksums[i >> 10];
        offsets[i] = v;
        cursor[i] = v;
    }
    if (i == 0) offsets[N] = *total;
}

// ---- K3: bucket edge ids by dst ----
__global__ void k_fill(const int* __restrict__ edge_dst, int* __restrict__ cursor,
                       int* __restrict__ edge_ids, int E) {
    int e = blockIdx.x * 256 + threadIdx.x;
    if (e >= E) return;
    int pos = atomicAdd(&cursor[edge_dst[e]], 1);
    edge_ids[pos] = e;
}

// ---- K5: per-node fused softmax + aggregate, write f32 out ----
__global__ __launch_bounds__(256) void k_out(
    const float2* __restrict__ hidden,
    const float*  __restrict__ a_buf,    // leaky-relu'd logits, E*8
    const int*    __restrict__ offsets,
    const int*    __restrict__ edge_ids,
    float2*       __restrict__ out,      // f32 (N,8,64) = N*8*32 float2
    int N)
{
    int tid = threadIdx.x;
    int n = blockIdx.x * 8 + (tid >> 5);
    if (n >= N) return;
    int lane = tid & 31;
    int beg = offsets[n], end = offsets[n + 1];

    if (beg == end) {   // isolated node: segment_sum over empty set = 0
        float2 z = make_float2(0.f, 0.f);
        #pragma unroll
        for (int hh = 0; hh < NUM_HEADS; ++hh)
            out[((size_t)n * 8 + hh) * 32 + lane] = z;
        return;
    }

    const float4* a4 = (const float4*)a_buf;
    // pass 1: per-head max over this node's edges
    float4 m0 = make_float4(-1e30f, -1e30f, -1e30f, -1e30f);
    float4 m1 = m0;
    for (int j = beg; j < end; ++j) {
        int e = edge_ids[j];
        float4 x0 = a4[(size_t)e * 2], x1 = a4[(size_t)e * 2 + 1];
        m0.x = fmaxf(m0.x, x0.x); m0.y = fmaxf(m0.y, x0.y);
        m0.z = fmaxf(m0.z, x0.z); m0.w = fmaxf(m0.w, x0.w);
        m1.x = fmaxf(m1.x, x1.x); m1.y = fmaxf(m1.y, x1.y);
        m1.z = fmaxf(m1.z, x1.z); m1.w = fmaxf(m1.w, x1.w);
    }
    // pass 2: exp-weights, denominator, weighted hidden accumulate
    float4 d0 = make_float4(0.f, 0.f, 0.f, 0.f), d1 = d0;
    float2 acc[NUM_HEADS];
    #pragma unroll
    for (int hh = 0; hh < NUM_HEADS; ++hh) acc[hh] = make_float2(0.f, 0.f);
    for (int j = beg; j < end; ++j) {
        int e = edge_ids[j];
        float4 x0 = a4[(size_t)e * 2], x1 = a4[(size_t)e * 2 + 1];
        float w0x = __expf(x0.x - m0.x), w0y = __expf(x0.y - m0.y);
        float w0z = __expf(x0.z - m0.z), w0w = __expf(x0.w - m0.w);
        float w1x = __expf(x1.x - m1.x), w1y = __expf(x1.y - m1.y);
        float w1z = __expf(x1.z - m1.z), w1w = __expf(x1.w - m1.w);
        d0.x += w0x; d0.y += w0y; d0.z += w0z; d0.w += w0w;
        d1.x += w1x; d1.y += w1y; d1.z += w1z; d1.w += w1w;
        float2 hv = hidden[(size_t)e * 32 + lane];
        acc[0].x += hv.x * w0x; acc[0].y += hv.y * w0x;
        acc[1].x += hv.x * w0y; acc[1].y += hv.y * w0y;
        acc[2].x += hv.x * w0z; acc[2].y += hv.y * w0z;
        acc[3].x += hv.x * w0w; acc[3].y += hv.y * w0w;
        acc[4].x += hv.x * w1x; acc[4].y += hv.y * w1x;
        acc[5].x += hv.x * w1y; acc[5].y += hv.y * w1y;
        acc[6].x += hv.x * w1z; acc[6].y += hv.y * w1z;
        acc[7].x += hv.x * w1w; acc[7].y += hv.y * w1w;
    }
    float r[NUM_HEADS] = {1.f/d0.x, 1.f/d0.y, 1.f/d0.z, 1.f/d0.w,
                          1.f/d1.x, 1.f/d1.y, 1.f/d1.z, 1.f/d1.w};
    #pragma unroll
    for (int hh = 0; hh < NUM_HEADS; ++hh) {
        float2 v = make_float2(acc[hh].x * r[hh], acc[hh].y * r[hh]);
        out[((size_t)n * 8 + hh) * 32 + lane] = v;
    }
}

extern "C" void kernel_launch(void* const* d_in, const int* in_sizes, int n_in,
                              void* d_out, int out_size, void* d_ws, size_t ws_size,
                              hipStream_t stream) {
    const float2* feat = (const float2*)d_in[0];   // features f32 (N,64)
    const float2* rvec = (const float2*)d_in[1];   // r_vec f32 (2,32,2)
    const float2* w1   = (const float2*)d_in[2];   // attn1_w f32 (8,64)
    const float2* w2   = (const float2*)d_in[3];   // attn2 f32 (1,8,64)
    const int4*   emi  = (const int4*)d_in[4];     // (E,4) int32
    const int* edge_dst = (const int*)d_in[5];     // (E,) int32

    int N = in_sizes[0] / 64;
    int E = in_sizes[4] / 4;
    int nTiles = (N + 1023) / 1024;                // N=100k -> 98 (<=1024)

    char* w = (char*)d_ws;
    float*    hidden   = (float*)w;                         // E*64 f32
    float*    a_buf    = hidden + (size_t)E * 64;           // E*8 f32
    int*      counts   = (int*)(a_buf + (size_t)E * 8);     // N
    int*      offsets  = counts + N;                        // N+1
    int*      cursor   = offsets + N + 1;                   // N
    int*      edge_ids = cursor + N;                        // E
    int*      blocksums= edge_ids + E;                      // nTiles (pad 1024)
    int*      total    = blocksums + 1024;                  // 1

    hipMemsetAsync(counts, 0, (size_t)N * 4, stream);

    k_edge<<<(E + 7) / 8, 256, 0, stream>>>(feat, rvec, w1, w2, emi, edge_dst,
                                            (float2*)hidden, a_buf, counts, E);
    k_scan_a<<<nTiles, 256, 0, stream>>>(counts, offsets, blocksums, N);
    k_scan_b<<<1, 1024, 0, stream>>>(blocksums, total, nTiles);
    k_scan_c<<<(N + 255) / 256, 256, 0, stream>>>(offsets, cursor, blocksums, total, N);
    k_fill<<<(E + 255) / 256, 256, 0, stream>>>(edge_dst, cursor, edge_ids, E);
    k_out<<<(N + 7) / 8, 256, 0, stream>>>((const float2*)hidden, a_buf,
                                           offsets, edge_ids, (float2*)d_out, N);
}